// Round 5
// baseline (543.753 us; speedup 1.0000x reference)
//
#include <hip/hip_runtime.h>

#define F 128
#define BSH 7                 // 128 nodes per coarse bucket
#define BWIDTH (1 << BSH)
#define MAX_NBKT 1024         // supports n <= 131072
#define P3CAP 3072            // max edges/bucket (mean ~2046, sd ~45 -> 22 sigma)
#define XPAD 136              // 128 + 8 bf16 pad: 272B row stride, 2-way alias only

typedef unsigned int uint;
typedef unsigned short ushort;
typedef unsigned long long u64;

typedef __attribute__((ext_vector_type(8))) short bf16x8;
typedef __attribute__((ext_vector_type(4))) float f32x4;

union U4B8 { uint4 u; bf16x8 v; };

// round-to-nearest-even f32 -> bf16 (values finite; no NaN handling needed)
static __device__ inline ushort f2bf(float f) {
    uint u = __float_as_uint(f);
    return (ushort)((u + 0x7FFF + ((u >> 16) & 1)) >> 16);
}
static __device__ inline float bf2f(ushort h) {
    return __uint_as_float((uint)h << 16);
}

// ---------------------------------------------------------------------------
// K1: blocks [0,G): per-chunk LDS histogram over coarse buckets (dst>>7).
//     blocks [G,G+8): pack W into MFMA B-frag layout (split bf16 hi/lo,
//     column-pair permuted). Block 0 also resets K2's arrival counter.
// ---------------------------------------------------------------------------
__global__ __launch_bounds__(256) void count_pack_kernel(
        const int* __restrict__ dst, const float* __restrict__ W,
        int* __restrict__ cnt_g, uint4* __restrict__ wphi,
        uint4* __restrict__ wplo, int* __restrict__ k2ctr,
        int e, int ce, int G) {
    __shared__ int hist[MAX_NBKT];
    int t = threadIdx.x;
    int blk = blockIdx.x;
    if (blk >= G) {
        int idx = (blk - G) * 256 + t;    // 0..2047
        int l = idx & 63, s = (idx >> 6) & 3, tt = idx >> 8;
        int p = tt >> 1, q = tt & 1;
        int col = 32 * p + 2 * (l & 15) + q;
        int kbase = 32 * s + (l >> 4) * 8;
        uint hi[8], lo[8];
        #pragma unroll
        for (int j = 0; j < 8; ++j) {
            float wv = W[(size_t)(kbase + j) * F + col];
            ushort h = f2bf(wv);
            lo[j] = f2bf(wv - bf2f(h));
            hi[j] = h;
        }
        uint4 vh, vl;
        vh.x = hi[0] | (hi[1] << 16); vh.y = hi[2] | (hi[3] << 16);
        vh.z = hi[4] | (hi[5] << 16); vh.w = hi[6] | (hi[7] << 16);
        vl.x = lo[0] | (lo[1] << 16); vl.y = lo[2] | (lo[3] << 16);
        vl.z = lo[4] | (lo[5] << 16); vl.w = lo[6] | (lo[7] << 16);
        wphi[idx] = vh;
        wplo[idx] = vl;
        return;
    }
    if (blk == 0 && t == 0) k2ctr[0] = 0;   // visible to K2 via kernel boundary
    for (int i = t; i < G; i += 256) hist[i] = 0;
    __syncthreads();
    int e0 = blk * ce;
    for (int j = 0; j < ce; j += 256) {
        int k = j + t;
        if (k < ce) {
            int i = e0 + k;
            if (i < e) atomicAdd(&hist[dst[i] >> BSH], 1);
        }
    }
    __syncthreads();
    for (int i = t; i < G; i += 256)
        cnt_g[(size_t)blk * G + i] = hist[i];   // [chunk][bucket], 1-writer rows
}

// ---------------------------------------------------------------------------
// K2: block b scans bucket b's counts across G chunks (scanA) -> within_T
//     [bucket][chunk] + totals[b]. Last-arriving block (agent-scope counter,
//     deadlock-free: no spinning) runs scanB over totals -> bbase[0..G], and
//     resets K3's barrier counter.
// ---------------------------------------------------------------------------
__global__ __launch_bounds__(256) void scan_kernel(
        const int* __restrict__ cnt_g, int* __restrict__ within_T,
        int* __restrict__ totals, int* __restrict__ bbase,
        int* __restrict__ k2ctr, int* __restrict__ k3ctr, int G) {
    __shared__ int sc[256];
    __shared__ int lastflag;
    int t = threadIdx.x, b = blockIdx.x;
    int j0 = t * 4;
    int v0 = 0, v1 = 0, v2 = 0, v3 = 0;
    if (j0 < G)     v0 = cnt_g[(size_t)(j0)     * G + b];
    if (j0 + 1 < G) v1 = cnt_g[(size_t)(j0 + 1) * G + b];
    if (j0 + 2 < G) v2 = cnt_g[(size_t)(j0 + 2) * G + b];
    if (j0 + 3 < G) v3 = cnt_g[(size_t)(j0 + 3) * G + b];
    int run = v0 + v1 + v2 + v3;
    sc[t] = run;
    __syncthreads();
    for (int off = 1; off < 256; off <<= 1) {
        int u = (t >= off) ? sc[t - off] : 0;
        __syncthreads();
        sc[t] += u;
        __syncthreads();
    }
    int excl = sc[t] - run;
    if (j0 < G)     within_T[(size_t)b * G + j0]     = excl;
    if (j0 + 1 < G) within_T[(size_t)b * G + j0 + 1] = excl + v0;
    if (j0 + 2 < G) within_T[(size_t)b * G + j0 + 2] = excl + v0 + v1;
    if (j0 + 3 < G) within_T[(size_t)b * G + j0 + 3] = excl + v0 + v1 + v2;
    if (t == 255)
        __hip_atomic_store(&totals[b], excl + run,
                           __ATOMIC_RELEASE, __HIP_MEMORY_SCOPE_AGENT);
    __syncthreads();
    if (t == 0) {
        int old = __hip_atomic_fetch_add(k2ctr, 1,
                                         __ATOMIC_ACQ_REL, __HIP_MEMORY_SCOPE_AGENT);
        lastflag = (old == G - 1);
    }
    __syncthreads();
    if (!lastflag) return;
    __threadfence();   // acquire side: see all blocks' totals
    int w0 = 0, w1 = 0, w2 = 0, w3 = 0;
    if (j0 < G)     w0 = __hip_atomic_load(&totals[j0],     __ATOMIC_RELAXED, __HIP_MEMORY_SCOPE_AGENT);
    if (j0 + 1 < G) w1 = __hip_atomic_load(&totals[j0 + 1], __ATOMIC_RELAXED, __HIP_MEMORY_SCOPE_AGENT);
    if (j0 + 2 < G) w2 = __hip_atomic_load(&totals[j0 + 2], __ATOMIC_RELAXED, __HIP_MEMORY_SCOPE_AGENT);
    if (j0 + 3 < G) w3 = __hip_atomic_load(&totals[j0 + 3], __ATOMIC_RELAXED, __HIP_MEMORY_SCOPE_AGENT);
    int run2 = w0 + w1 + w2 + w3;
    sc[t] = run2;
    __syncthreads();
    for (int off = 1; off < 256; off <<= 1) {
        int u = (t >= off) ? sc[t - off] : 0;
        __syncthreads();
        sc[t] += u;
        __syncthreads();
    }
    int excl2 = sc[t] - run2;
    if (j0 < G)     bbase[j0]     = excl2;
    if (j0 + 1 < G) bbase[j0 + 1] = excl2 + w0;
    if (j0 + 2 < G) bbase[j0 + 2] = excl2 + w0 + w1;
    if (j0 + 3 < G) bbase[j0 + 3] = excl2 + w0 + w1 + w2;
    if (t == 255) bbase[G] = excl2 + run2;   // == e
    if (t == 0) k3ctr[0] = 0;                // reset K3 barrier (boundary-visible)
}

// ---------------------------------------------------------------------------
// K3: scatter + GEMM + resident-grid barrier + bucket-build, one kernel.
// grid = G = 782 blocks, 4 blocks/CU by launch_bounds+LDS => all co-resident
// (1024 slots >= 782), so the single spin barrier is deadlock-safe. The GEMM
// (independent work) runs between arrive and wait, hiding the barrier.
// Cross-XCD: ebuf handoff via agent-scope atomics; barrier via threadfence +
// acq/rel agent atomics.
// ---------------------------------------------------------------------------
struct SmemA {   // bucket build
    int2 stage[P3CAP];
    int cnt[BWIDTH]; uint ws[BWIDTH]; float dvl[BWIDTH];
    int cur[BWIDTH]; int offsh[BWIDTH];
};
struct SmemG {   // gemm staging
    ushort xhi[64][XPAD];
    ushort xlo[64][XPAD];
};
union SmemU {
    SmemA a;            // 27136 B
    SmemG g;            // 34816 B (max)
    int cursor[MAX_NBKT];
};

__global__ __launch_bounds__(256, 4) void sgb_kernel(
        const int* __restrict__ src, const int* __restrict__ dst,
        const float* __restrict__ w, const float* __restrict__ x,
        const uint4* __restrict__ wphi, const uint4* __restrict__ wplo,
        const int* __restrict__ bbase, const int* __restrict__ within_T,
        int2* __restrict__ ebuf, ushort* __restrict__ hb,
        int* __restrict__ row_start, float* __restrict__ dinv,
        int* __restrict__ k3ctr, int n, int e, int ce, int G) {
    __shared__ SmemU u;
    int t = threadIdx.x, blk = blockIdx.x;
    u64* ebuf_u = (u64*)ebuf;

    // ---- phase 1: scatter chunk blk into bucket-grouped ebuf ----
    for (int i = t; i < G; i += 256)
        u.cursor[i] = bbase[i] + within_T[(size_t)i * G + blk];
    __syncthreads();
    int e0 = blk * ce;
    for (int j = 0; j < ce; j += 256) {
        int k = j + t;
        if (k < ce) {
            int i = e0 + k;
            if (i < e) {
                int d = dst[i];
                int pos = atomicAdd(&u.cursor[d >> BSH], 1);
                u64 pk = ((u64)(uint)__float_as_int(w[i]) << 32)
                       | (uint)(src[i] | ((d & (BWIDTH - 1)) << 17));
                __hip_atomic_store(&ebuf_u[pos], pk,
                                   __ATOMIC_RELAXED, __HIP_MEMORY_SCOPE_AGENT);
            }
        }
    }
    __syncthreads();
    if (t == 0) {
        __threadfence();   // publish this block's ebuf writes device-wide
        __hip_atomic_fetch_add(k3ctr, 1, __ATOMIC_ACQ_REL, __HIP_MEMORY_SCOPE_AGENT);
    }

    // ---- phase 2: GEMM h = x@W, grid-stride tiles (hides barrier wait) ----
    {
        int ntile = (n + 63) >> 6;
        int wv = t >> 6, l = t & 63;
        int mm = l & 15, quad = l >> 4;
        for (int tile = blk; tile < ntile; tile += G) {
            __syncthreads();   // LDS reuse guard (cursor / previous iter reads)
            int row0 = tile * 64;
            #pragma unroll
            for (int i = 0; i < 8; ++i) {
                int v = t + 256 * i;          // 0..2047 float4 slots
                int r = v >> 5, c4 = v & 31;
                int row = row0 + r;
                float4 val = (row < n) ? ((const float4*)x)[(size_t)row * 32 + c4]
                                       : make_float4(0.f, 0.f, 0.f, 0.f);
                ushort h0 = f2bf(val.x), h1 = f2bf(val.y), h2 = f2bf(val.z), h3 = f2bf(val.w);
                ushort l0 = f2bf(val.x - bf2f(h0)), l1 = f2bf(val.y - bf2f(h1));
                ushort l2 = f2bf(val.z - bf2f(h2)), l3 = f2bf(val.w - bf2f(h3));
                *(ushort4*)&u.g.xhi[r][c4 * 4] = make_ushort4(h0, h1, h2, h3);
                *(ushort4*)&u.g.xlo[r][c4 * 4] = make_ushort4(l0, l1, l2, l3);
            }
            __syncthreads();

            f32x4 acc[8];
            #pragma unroll
            for (int i = 0; i < 8; ++i) acc[i] = (f32x4){0.f, 0.f, 0.f, 0.f};

            #pragma unroll
            for (int s = 0; s < 4; ++s) {
                bf16x8 ahi = *(const bf16x8*)&u.g.xhi[16 * wv + mm][32 * s + quad * 8];
                bf16x8 alo = *(const bf16x8*)&u.g.xlo[16 * wv + mm][32 * s + quad * 8];
                #pragma unroll
                for (int tt = 0; tt < 8; ++tt) {
                    int widx = (tt * 4 + s) * 64 + l;
                    U4B8 bh, bl;
                    bh.u = wphi[widx];
                    bl.u = wplo[widx];
                    acc[tt] = __builtin_amdgcn_mfma_f32_16x16x32_bf16(ahi, bh.v, acc[tt], 0, 0, 0);
                    acc[tt] = __builtin_amdgcn_mfma_f32_16x16x32_bf16(alo, bh.v, acc[tt], 0, 0, 0);
                    acc[tt] = __builtin_amdgcn_mfma_f32_16x16x32_bf16(ahi, bl.v, acc[tt], 0, 0, 0);
                }
            }

            // epilogue: C/D layout col=lane&15 (permuted), row=quad*4+reg.
            #pragma unroll
            for (int r = 0; r < 4; ++r) {
                int row = row0 + 16 * wv + quad * 4 + r;
                if (row < n) {
                    uint* outp = (uint*)hb + (size_t)row * 64;
                    #pragma unroll
                    for (int p = 0; p < 4; ++p) {
                        uint vp = (uint)f2bf(acc[2 * p][r]) |
                                  ((uint)f2bf(acc[2 * p + 1][r]) << 16);
                        outp[p * 16 + mm] = vp;   // coalesced per quad (64B)
                    }
                }
            }
        }
    }

    // ---- barrier wait: all chunks scattered (usually already satisfied) ----
    __syncthreads();
    if (t == 0) {
        while (__hip_atomic_load(k3ctr, __ATOMIC_ACQUIRE, __HIP_MEMORY_SCOPE_AGENT) < G)
            __builtin_amdgcn_s_sleep(8);
        __threadfence();
    }
    __syncthreads();

    // ---- phase 3: build bucket blk (count/wsum/dinv/row_start + in-place CSR) --
    {
        int r0 = bbase[blk], r1 = bbase[blk + 1];
        int m = r1 - r0;
        if (m > P3CAP) m = P3CAP;   // statistically impossible for this input
        if (t < BWIDTH) { u.a.cnt[t] = 0; u.a.ws[t] = 0u; }
        __syncthreads();
        for (int i = t; i < m; i += 256) {
            u64 pk = __hip_atomic_load(&ebuf_u[r0 + i],
                                       __ATOMIC_RELAXED, __HIP_MEMORY_SCOPE_AGENT);
            int2 ed;
            ed.x = (int)(uint)(pk & 0xFFFFFFFFu);
            ed.y = (int)(uint)(pk >> 32);
            u.a.stage[i] = ed;
            int bl = (ed.x >> 17) & (BWIDTH - 1);
            atomicAdd(&u.a.cnt[bl], 1);
            atomicAdd(&u.a.ws[bl], (uint)(__int_as_float(ed.y) * 16777216.0f));
        }
        __syncthreads();
        if (t < BWIDTH) u.a.offsh[t] = u.a.cnt[t];
        __syncthreads();
        for (int off = 1; off < BWIDTH; off <<= 1) {
            int uu = 0;
            if (t < BWIDTH && t >= off) uu = u.a.offsh[t - off];
            __syncthreads();
            if (t < BWIDTH) u.a.offsh[t] += uu;
            __syncthreads();
        }
        if (t < BWIDTH) {
            int excl = u.a.offsh[t] - u.a.cnt[t];
            u.a.cur[t] = excl;
            float dv = rsqrtf(1.0f + (float)u.a.ws[t] * (1.0f / 16777216.0f));
            u.a.dvl[t] = dv;
            int d = (blk << BSH) + t;
            if (d < n) {
                row_start[d] = r0 + excl;
                dinv[d] = dv;
                if (d == n - 1) row_start[n] = r1;
            }
        }
        __syncthreads();
        for (int i = t; i < m; i += 256) {
            int2 ed = u.a.stage[i];
            int bl = (ed.x >> 17) & (BWIDTH - 1);
            int pos = atomicAdd(&u.a.cur[bl], 1);
            ebuf[r0 + pos] = make_int2(ed.x & 0x1FFFF,
                                       __float_as_int(__int_as_float(ed.y) * u.a.dvl[bl]));
        }
    }
}

// ---------------------------------------------------------------------------
// K4: aggregate — verified round-1 form (fetch-path BW-bound at its roofline).
// One wave per node, 2 bf16 features per lane; readlane edge broadcast, 8-deep
// gather batch for MLP. csr entry = (src, w*dinv[dst]); dinv[src] gathered
// (400 KB, cache-resident).
// ---------------------------------------------------------------------------
__global__ __launch_bounds__(256) void aggregate_kernel(
        const ushort* __restrict__ hb, const int* __restrict__ row_start,
        const int2* __restrict__ csr, const float* __restrict__ dinv,
        const float* __restrict__ b,
        float* __restrict__ out_emb, float* __restrict__ out_relu, int n) {
    int wave = threadIdx.x >> 6;
    int lane = threadIdx.x & 63;
    int i = blockIdx.x * 4 + wave;
    if (i >= n) return;
    int lo = row_start[i], hi = row_start[i + 1];
    float di = dinv[i];
    const uint* h32 = (const uint*)hb;   // one dword = features {2*lane, 2*lane+1}
    uint hvu = h32[(size_t)i * 64 + lane];
    float2 bv = ((const float2*)b)[lane];
    float2 acc;
    acc.x = fmaf(__uint_as_float(hvu << 16) * di, di, bv.x);          // self-loop
    acc.y = fmaf(__uint_as_float(hvu & 0xFFFF0000u) * di, di, bv.y);
    for (int c = lo; c < hi; c += 64) {
        int m = min(64, hi - c);
        int sv = 0, nvi = 0;   // lanes >= m keep (src=0, norm=0) -> harmless padding
        if (lane < m) {
            int2 en = csr[c + lane];
            sv = en.x;
            nvi = __float_as_int(__int_as_float(en.y) * dinv[sv]);
        }
        int mp = (m + 7) & ~7;
        for (int j = 0; j < mp; j += 8) {
            int ss[8]; float nw[8]; uint g[8];
            #pragma unroll
            for (int u = 0; u < 8; ++u) {
                ss[u] = __builtin_amdgcn_readlane(sv, j + u);
                nw[u] = __uint_as_float((uint)__builtin_amdgcn_readlane(nvi, j + u));
            }
            #pragma unroll
            for (int u = 0; u < 8; ++u)
                g[u] = h32[(size_t)ss[u] * 64 + lane];   // 8 independent 256B row gathers
            #pragma unroll
            for (int u = 0; u < 8; ++u) {
                acc.x = fmaf(__uint_as_float(g[u] << 16), nw[u], acc.x);
                acc.y = fmaf(__uint_as_float(g[u] & 0xFFFF0000u), nw[u], acc.y);
            }
        }
    }
    ((float2*)out_emb)[(size_t)i * 64 + lane] = acc;
    ((float2*)out_relu)[(size_t)i * 64 + lane] =
        make_float2(fmaxf(acc.x, 0.f), fmaxf(acc.y, 0.f));
}

extern "C" void kernel_launch(void* const* d_in, const int* in_sizes, int n_in,
                              void* d_out, int out_size, void* d_ws, size_t ws_size,
                              hipStream_t stream) {
    const float* x  = (const float*)d_in[0];
    const float* W  = (const float*)d_in[1];
    const float* b  = (const float*)d_in[2];
    const int*   ei = (const int*)d_in[4];
    const float* ew = (const float*)d_in[5];

    int n = in_sizes[0] / F;
    int e = in_sizes[4] / 2;
    const int* src = ei;
    const int* dst = ei + e;

    float* out_emb  = (float*)d_out;
    float* out_relu = out_emb + (size_t)n * F;

    int G  = (n + BWIDTH - 1) >> BSH;   // 782 buckets/chunks (<= MAX_NBKT)
    int ce = (e + G - 1) / G;           // 2047 edges per chunk

    // workspace layout (~44 MB):
    ushort* hb       = (ushort*)d_ws;                     // n*F bf16 (25.6 MB)
    int2*   ebuf     = (int2*)(hb + (size_t)n * F);       // e int2 (12.8 MB) -> csr in place
    uint4*  wphi     = (uint4*)(ebuf + e);                // 2048 uint4 (32 KB)
    uint4*  wplo     = wphi + 2048;                       // 2048 uint4 (32 KB)
    int*    cnt_g    = (int*)(wplo + 2048);               // G*G (2.45 MB) [chunk][bucket]
    int*    within_T = cnt_g + (size_t)G * G;             // G*G (2.45 MB) [bucket][chunk]
    int*    totals   = within_T + (size_t)G * G;          // G
    int*    bbase    = totals + G;                        // G+1 (+pad)
    int*    row_start= bbase + G + 4;                     // n+1 (+pad)
    float*  dinv     = (float*)(row_start + n + 4);       // n
    int*    ctrs     = (int*)(dinv + n);                  // [0]=k2ctr, [1]=k3ctr

    count_pack_kernel<<<G + 8, 256, 0, stream>>>(dst, W, cnt_g, wphi, wplo,
                                                 &ctrs[0], e, ce, G);
    scan_kernel<<<G, 256, 0, stream>>>(cnt_g, within_T, totals, bbase,
                                       &ctrs[0], &ctrs[1], G);
    sgb_kernel<<<G, 256, 0, stream>>>(src, dst, ew, x, wphi, wplo, bbase, within_T,
                                      ebuf, hb, row_start, dinv, &ctrs[1],
                                      n, e, ce, G);
    aggregate_kernel<<<(n + 3) / 4, 256, 0, stream>>>(hb, row_start, ebuf, dinv, b,
                                                      out_emb, out_relu, n);
}

// Round 6
// 338.861 us; speedup vs baseline: 1.6047x; 1.6047x over previous
//
#include <hip/hip_runtime.h>

#define F 128
#define BSH 7                 // 128 nodes per coarse bucket
#define BWIDTH (1 << BSH)
#define MAX_NBKT 1024         // supports n <= 131072
#define P3CAP 4096            // max edges/bucket (mean ~2046, sd ~45 -> 43 sigma)
#define XPAD 136              // 128 + 8 bf16 pad: 272B row stride, 2-way alias only

typedef unsigned int uint;
typedef unsigned short ushort;

typedef __attribute__((ext_vector_type(8))) short bf16x8;
typedef __attribute__((ext_vector_type(4))) float f32x4;

union U4B8 { uint4 u; bf16x8 v; };

// round-to-nearest-even f32 -> bf16 (values finite; no NaN handling needed)
static __device__ inline ushort f2bf(float f) {
    uint u = __float_as_uint(f);
    return (ushort)((u + 0x7FFF + ((u >> 16) & 1)) >> 16);
}
static __device__ inline float bf2f(ushort h) {
    return __uint_as_float((uint)h << 16);
}

// ---------------------------------------------------------------------------
// K1: blocks [0,G): per-chunk LDS histogram over coarse buckets (dst>>7).
//     blocks [G,G+8): pack W into MFMA B-frag layout (split bf16 hi/lo,
//     column-pair permuted). Block 0 resets K2's arrival counter.
//     All cross-kernel data via plain stores: the launch boundary publishes.
// ---------------------------------------------------------------------------
__global__ __launch_bounds__(256) void count_pack_kernel(
        const int* __restrict__ dst, const float* __restrict__ W,
        int* __restrict__ cnt_g, uint4* __restrict__ wphi,
        uint4* __restrict__ wplo, int* __restrict__ k2ctr,
        int e, int ce, int G) {
    __shared__ int hist[MAX_NBKT];
    int t = threadIdx.x;
    int blk = blockIdx.x;
    if (blk >= G) {
        int idx = (blk - G) * 256 + t;    // 0..2047
        int l = idx & 63, s = (idx >> 6) & 3, tt = idx >> 8;
        int p = tt >> 1, q = tt & 1;
        int col = 32 * p + 2 * (l & 15) + q;
        int kbase = 32 * s + (l >> 4) * 8;
        uint hi[8], lo[8];
        #pragma unroll
        for (int j = 0; j < 8; ++j) {
            float wv = W[(size_t)(kbase + j) * F + col];
            ushort h = f2bf(wv);
            lo[j] = f2bf(wv - bf2f(h));
            hi[j] = h;
        }
        uint4 vh, vl;
        vh.x = hi[0] | (hi[1] << 16); vh.y = hi[2] | (hi[3] << 16);
        vh.z = hi[4] | (hi[5] << 16); vh.w = hi[6] | (hi[7] << 16);
        vl.x = lo[0] | (lo[1] << 16); vl.y = lo[2] | (lo[3] << 16);
        vl.z = lo[4] | (lo[5] << 16); vl.w = lo[6] | (lo[7] << 16);
        wphi[idx] = vh;
        wplo[idx] = vl;
        return;
    }
    if (blk == 0 && t == 0) k2ctr[0] = 0;   // visible to K2 via kernel boundary
    for (int i = t; i < G; i += 256) hist[i] = 0;
    __syncthreads();
    int e0 = blk * ce;
    for (int j = 0; j < ce; j += 256) {
        int k = j + t;
        if (k < ce) {
            int i = e0 + k;
            if (i < e) atomicAdd(&hist[dst[i] >> BSH], 1);
        }
    }
    __syncthreads();
    for (int i = t; i < G; i += 256)
        cnt_g[(size_t)blk * G + i] = hist[i];   // [chunk][bucket], 1-writer rows
}

// ---------------------------------------------------------------------------
// K2: block b scans bucket b's counts across G chunks (scanA) -> within_T
//     [bucket][chunk] + totals[b]. Last-arriving block (agent-scope counter on
//     ONE int — control plane only, deadlock-free: no spinning) runs scanB over
//     totals -> bbase[0..G]. Verified correct in round 5.
// ---------------------------------------------------------------------------
__global__ __launch_bounds__(256) void scan_kernel(
        const int* __restrict__ cnt_g, int* __restrict__ within_T,
        int* __restrict__ totals, int* __restrict__ bbase,
        int* __restrict__ k2ctr, int G) {
    __shared__ int sc[256];
    __shared__ int lastflag;
    int t = threadIdx.x, b = blockIdx.x;
    int j0 = t * 4;
    int v0 = 0, v1 = 0, v2 = 0, v3 = 0;
    if (j0 < G)     v0 = cnt_g[(size_t)(j0)     * G + b];
    if (j0 + 1 < G) v1 = cnt_g[(size_t)(j0 + 1) * G + b];
    if (j0 + 2 < G) v2 = cnt_g[(size_t)(j0 + 2) * G + b];
    if (j0 + 3 < G) v3 = cnt_g[(size_t)(j0 + 3) * G + b];
    int run = v0 + v1 + v2 + v3;
    sc[t] = run;
    __syncthreads();
    for (int off = 1; off < 256; off <<= 1) {
        int u = (t >= off) ? sc[t - off] : 0;
        __syncthreads();
        sc[t] += u;
        __syncthreads();
    }
    int excl = sc[t] - run;
    if (j0 < G)     within_T[(size_t)b * G + j0]     = excl;
    if (j0 + 1 < G) within_T[(size_t)b * G + j0 + 1] = excl + v0;
    if (j0 + 2 < G) within_T[(size_t)b * G + j0 + 2] = excl + v0 + v1;
    if (j0 + 3 < G) within_T[(size_t)b * G + j0 + 3] = excl + v0 + v1 + v2;
    if (t == 255)
        __hip_atomic_store(&totals[b], excl + run,
                           __ATOMIC_RELEASE, __HIP_MEMORY_SCOPE_AGENT);
    __syncthreads();
    if (t == 0) {
        int old = __hip_atomic_fetch_add(k2ctr, 1,
                                         __ATOMIC_ACQ_REL, __HIP_MEMORY_SCOPE_AGENT);
        lastflag = (old == G - 1);
    }
    __syncthreads();
    if (!lastflag) return;
    __threadfence();   // acquire side: see all blocks' totals
    int w0 = 0, w1 = 0, w2 = 0, w3 = 0;
    if (j0 < G)     w0 = __hip_atomic_load(&totals[j0],     __ATOMIC_RELAXED, __HIP_MEMORY_SCOPE_AGENT);
    if (j0 + 1 < G) w1 = __hip_atomic_load(&totals[j0 + 1], __ATOMIC_RELAXED, __HIP_MEMORY_SCOPE_AGENT);
    if (j0 + 2 < G) w2 = __hip_atomic_load(&totals[j0 + 2], __ATOMIC_RELAXED, __HIP_MEMORY_SCOPE_AGENT);
    if (j0 + 3 < G) w3 = __hip_atomic_load(&totals[j0 + 3], __ATOMIC_RELAXED, __HIP_MEMORY_SCOPE_AGENT);
    int run2 = w0 + w1 + w2 + w3;
    sc[t] = run2;
    __syncthreads();
    for (int off = 1; off < 256; off <<= 1) {
        int u = (t >= off) ? sc[t - off] : 0;
        __syncthreads();
        sc[t] += u;
        __syncthreads();
    }
    int excl2 = sc[t] - run2;
    if (j0 < G)     bbase[j0]     = excl2;
    if (j0 + 1 < G) bbase[j0 + 1] = excl2 + w0;
    if (j0 + 2 < G) bbase[j0 + 2] = excl2 + w0 + w1;
    if (j0 + 3 < G) bbase[j0 + 3] = excl2 + w0 + w1 + w2;
    if (t == 255) bbase[G] = excl2 + run2;   // == e
}

// ---------------------------------------------------------------------------
// K3: scatter (blocks [0,G)) + GEMM (blocks [G,G+ntile)) — two INDEPENDENT
// workloads sharing one launch; zero cross-block communication; plain stores.
// The K3->K4 kernel boundary publishes ebuf/hb (cheap coherence — round-5
// lesson: per-access agent-scope data-plane ops are 10x worse).
// ---------------------------------------------------------------------------
union SmemU3 {
    int cursor[MAX_NBKT];                                 // scatter path (4 KB)
    struct { ushort xhi[64][XPAD]; ushort xlo[64][XPAD]; } g;   // gemm (34.8 KB)
};

__global__ __launch_bounds__(256) void scatter_gemm_kernel(
        const int* __restrict__ src, const int* __restrict__ dst,
        const float* __restrict__ w, const float* __restrict__ x,
        const uint4* __restrict__ wphi, const uint4* __restrict__ wplo,
        const int* __restrict__ bbase, const int* __restrict__ within_T,
        int2* __restrict__ ebuf, ushort* __restrict__ hb,
        int n, int e, int ce, int G) {
    __shared__ SmemU3 u;
    int t = threadIdx.x, blk = blockIdx.x;

    if (blk < G) {
        // ---- scatter chunk blk into bucket-grouped ebuf (LDS cursor ranks) ----
        for (int i = t; i < G; i += 256)
            u.cursor[i] = bbase[i] + within_T[(size_t)i * G + blk];
        __syncthreads();
        int e0 = blk * ce;
        for (int j = 0; j < ce; j += 256) {
            int k = j + t;
            if (k < ce) {
                int i = e0 + k;
                if (i < e) {
                    int d = dst[i];
                    int pos = atomicAdd(&u.cursor[d >> BSH], 1);
                    ebuf[pos] = make_int2(src[i] | ((d & (BWIDTH - 1)) << 17),
                                          __float_as_int(w[i]));
                }
            }
        }
        return;
    }

    // ---- GEMM h = x@W, tile (blk - G); split-bf16 hi/lo MFMA ----
    int row0 = (blk - G) * 64;
    #pragma unroll
    for (int i = 0; i < 8; ++i) {
        int v = t + 256 * i;          // 0..2047 float4 slots
        int r = v >> 5, c4 = v & 31;
        int row = row0 + r;
        float4 val = (row < n) ? ((const float4*)x)[(size_t)row * 32 + c4]
                               : make_float4(0.f, 0.f, 0.f, 0.f);
        ushort h0 = f2bf(val.x), h1 = f2bf(val.y), h2 = f2bf(val.z), h3 = f2bf(val.w);
        ushort l0 = f2bf(val.x - bf2f(h0)), l1 = f2bf(val.y - bf2f(h1));
        ushort l2 = f2bf(val.z - bf2f(h2)), l3 = f2bf(val.w - bf2f(h3));
        *(ushort4*)&u.g.xhi[r][c4 * 4] = make_ushort4(h0, h1, h2, h3);
        *(ushort4*)&u.g.xlo[r][c4 * 4] = make_ushort4(l0, l1, l2, l3);
    }
    __syncthreads();

    int wv = t >> 6, l = t & 63;
    int mm = l & 15, quad = l >> 4;
    f32x4 acc[8];
    #pragma unroll
    for (int i = 0; i < 8; ++i) acc[i] = (f32x4){0.f, 0.f, 0.f, 0.f};

    #pragma unroll
    for (int s = 0; s < 4; ++s) {
        bf16x8 ahi = *(const bf16x8*)&u.g.xhi[16 * wv + mm][32 * s + quad * 8];
        bf16x8 alo = *(const bf16x8*)&u.g.xlo[16 * wv + mm][32 * s + quad * 8];
        #pragma unroll
        for (int tt = 0; tt < 8; ++tt) {
            int widx = (tt * 4 + s) * 64 + l;
            U4B8 bh, bl;
            bh.u = wphi[widx];
            bl.u = wplo[widx];
            acc[tt] = __builtin_amdgcn_mfma_f32_16x16x32_bf16(ahi, bh.v, acc[tt], 0, 0, 0);
            acc[tt] = __builtin_amdgcn_mfma_f32_16x16x32_bf16(alo, bh.v, acc[tt], 0, 0, 0);
            acc[tt] = __builtin_amdgcn_mfma_f32_16x16x32_bf16(ahi, bl.v, acc[tt], 0, 0, 0);
        }
    }

    // epilogue: C/D layout col=lane&15 (permuted), row=quad*4+reg.
    #pragma unroll
    for (int r = 0; r < 4; ++r) {
        int row = row0 + 16 * wv + quad * 4 + r;
        if (row < n) {
            uint* outp = (uint*)hb + (size_t)row * 64;
            #pragma unroll
            for (int p = 0; p < 4; ++p) {
                uint vp = (uint)f2bf(acc[2 * p][r]) |
                          ((uint)f2bf(acc[2 * p + 1][r]) << 16);
                outp[p * 16 + mm] = vp;   // coalesced per quad (64B)
            }
        }
    }
}

// ---------------------------------------------------------------------------
// K4: bucket build (block b owns bucket b) — verified round-1 form, plain
// loads/stores. Stage bucket edges in LDS, per-node count + weight-sum (LDS
// atomics, 2^-24 fixed pt), local scan -> global row_start, dinv; then scatter
// final CSR IN PLACE: entry (src, w * dinv[dst]).
// ---------------------------------------------------------------------------
__global__ __launch_bounds__(256) void bucket_build_kernel(int2* __restrict__ ebuf,
                                                           const int* __restrict__ bbase,
                                                           int* __restrict__ row_start,
                                                           float* __restrict__ dinv,
                                                           int n, int nbkt) {
    __shared__ int2 stage[P3CAP];
    __shared__ int cnt[BWIDTH];
    __shared__ uint ws[BWIDTH];
    __shared__ float dvl[BWIDTH];
    __shared__ int cur[BWIDTH];
    __shared__ int offsh[BWIDTH];
    int b = blockIdx.x, t = threadIdx.x;
    int r0 = bbase[b], r1 = bbase[b + 1];
    int m = r1 - r0;
    if (m > P3CAP) m = P3CAP;   // statistically impossible for this input
    if (t < BWIDTH) { cnt[t] = 0; ws[t] = 0u; }
    __syncthreads();
    for (int i = t; i < m; i += 256) {
        int2 ed = ebuf[r0 + i];
        stage[i] = ed;
        int bl = (ed.x >> 17) & (BWIDTH - 1);
        atomicAdd(&cnt[bl], 1);
        atomicAdd(&ws[bl], (uint)(__int_as_float(ed.y) * 16777216.0f));
    }
    __syncthreads();
    if (t < BWIDTH) offsh[t] = cnt[t];
    __syncthreads();
    for (int off = 1; off < BWIDTH; off <<= 1) {   // inclusive scan of counts
        int u = 0;
        if (t < BWIDTH && t >= off) u = offsh[t - off];
        __syncthreads();
        if (t < BWIDTH) offsh[t] += u;
        __syncthreads();
    }
    if (t < BWIDTH) {
        int excl = offsh[t] - cnt[t];
        cur[t] = excl;
        float dv = rsqrtf(1.0f + (float)ws[t] * (1.0f / 16777216.0f));  // + self-loop
        dvl[t] = dv;
        int d = (b << BSH) + t;
        if (d < n) {
            row_start[d] = r0 + excl;
            dinv[d] = dv;
            if (d == n - 1) row_start[n] = r1;
        }
    }
    __syncthreads();
    for (int i = t; i < m; i += 256) {
        int2 ed = stage[i];
        int bl = (ed.x >> 17) & (BWIDTH - 1);
        int pos = atomicAdd(&cur[bl], 1);
        ebuf[r0 + pos] = make_int2(ed.x & 0x1FFFF,
                                   __float_as_int(__int_as_float(ed.y) * dvl[bl]));
    }
}

// ---------------------------------------------------------------------------
// K5: aggregate — verified round-1 form; at its random-gather fetch roofline
// (~4.2 TB/s effective, FETCH+WRITE compulsory). One wave per node, 2 bf16
// features per lane; readlane edge broadcast, 8-deep gather batch for MLP.
// ---------------------------------------------------------------------------
__global__ __launch_bounds__(256) void aggregate_kernel(
        const ushort* __restrict__ hb, const int* __restrict__ row_start,
        const int2* __restrict__ csr, const float* __restrict__ dinv,
        const float* __restrict__ b,
        float* __restrict__ out_emb, float* __restrict__ out_relu, int n) {
    int wave = threadIdx.x >> 6;
    int lane = threadIdx.x & 63;
    int i = blockIdx.x * 4 + wave;
    if (i >= n) return;
    int lo = row_start[i], hi = row_start[i + 1];
    float di = dinv[i];
    const uint* h32 = (const uint*)hb;   // one dword = features {2*lane, 2*lane+1}
    uint hvu = h32[(size_t)i * 64 + lane];
    float2 bv = ((const float2*)b)[lane];
    float2 acc;
    acc.x = fmaf(__uint_as_float(hvu << 16) * di, di, bv.x);          // self-loop
    acc.y = fmaf(__uint_as_float(hvu & 0xFFFF0000u) * di, di, bv.y);
    for (int c = lo; c < hi; c += 64) {
        int m = min(64, hi - c);
        int sv = 0, nvi = 0;   // lanes >= m keep (src=0, norm=0) -> harmless padding
        if (lane < m) {
            int2 en = csr[c + lane];
            sv = en.x;
            nvi = __float_as_int(__int_as_float(en.y) * dinv[sv]);
        }
        int mp = (m + 7) & ~7;
        for (int j = 0; j < mp; j += 8) {
            int ss[8]; float nw[8]; uint g[8];
            #pragma unroll
            for (int u = 0; u < 8; ++u) {
                ss[u] = __builtin_amdgcn_readlane(sv, j + u);
                nw[u] = __uint_as_float((uint)__builtin_amdgcn_readlane(nvi, j + u));
            }
            #pragma unroll
            for (int u = 0; u < 8; ++u)
                g[u] = h32[(size_t)ss[u] * 64 + lane];   // 8 independent 256B row gathers
            #pragma unroll
            for (int u = 0; u < 8; ++u) {
                acc.x = fmaf(__uint_as_float(g[u] << 16), nw[u], acc.x);
                acc.y = fmaf(__uint_as_float(g[u] & 0xFFFF0000u), nw[u], acc.y);
            }
        }
    }
    ((float2*)out_emb)[(size_t)i * 64 + lane] = acc;
    ((float2*)out_relu)[(size_t)i * 64 + lane] =
        make_float2(fmaxf(acc.x, 0.f), fmaxf(acc.y, 0.f));
}

extern "C" void kernel_launch(void* const* d_in, const int* in_sizes, int n_in,
                              void* d_out, int out_size, void* d_ws, size_t ws_size,
                              hipStream_t stream) {
    const float* x  = (const float*)d_in[0];
    const float* W  = (const float*)d_in[1];
    const float* b  = (const float*)d_in[2];
    const int*   ei = (const int*)d_in[4];
    const float* ew = (const float*)d_in[5];

    int n = in_sizes[0] / F;
    int e = in_sizes[4] / 2;
    const int* src = ei;
    const int* dst = ei + e;

    float* out_emb  = (float*)d_out;
    float* out_relu = out_emb + (size_t)n * F;

    int G  = (n + BWIDTH - 1) >> BSH;   // 782 buckets/chunks (<= MAX_NBKT)
    int ce = (e + G - 1) / G;           // 2047 edges per chunk
    int ntile = (n + 63) / 64;          // 1563 gemm tiles

    // workspace layout (~44 MB):
    ushort* hb       = (ushort*)d_ws;                     // n*F bf16 (25.6 MB)
    int2*   ebuf     = (int2*)(hb + (size_t)n * F);       // e int2 (12.8 MB) -> csr in place
    uint4*  wphi     = (uint4*)(ebuf + e);                // 2048 uint4 (32 KB)
    uint4*  wplo     = wphi + 2048;                       // 2048 uint4 (32 KB)
    int*    cnt_g    = (int*)(wplo + 2048);               // G*G (2.45 MB) [chunk][bucket]
    int*    within_T = cnt_g + (size_t)G * G;             // G*G (2.45 MB) [bucket][chunk]
    int*    totals   = within_T + (size_t)G * G;          // G
    int*    bbase    = totals + G;                        // G+1 (+pad)
    int*    row_start= bbase + G + 4;                     // n+1 (+pad)
    float*  dinv     = (float*)(row_start + n + 4);       // n
    int*    ctrs     = (int*)(dinv + n);                  // [0]=k2ctr

    count_pack_kernel<<<G + 8, 256, 0, stream>>>(dst, W, cnt_g, wphi, wplo,
                                                 &ctrs[0], e, ce, G);
    scan_kernel<<<G, 256, 0, stream>>>(cnt_g, within_T, totals, bbase,
                                       &ctrs[0], G);
    scatter_gemm_kernel<<<G + ntile, 256, 0, stream>>>(src, dst, ew, x, wphi, wplo,
                                                       bbase, within_T, ebuf, hb,
                                                       n, e, ce, G);
    bucket_build_kernel<<<G, 256, 0, stream>>>(ebuf, bbase, row_start, dinv, n, G);
    aggregate_kernel<<<(n + 3) / 4, 256, 0, stream>>>(hb, row_start, ebuf, dinv, b,
                                                      out_emb, out_relu, n);
}